// Round 6
// baseline (29145.053 us; speedup 1.0000x reference)
//
#include <hip/hip_runtime.h>
#include <hip/hip_bf16.h>
#include <math.h>

typedef __hip_bfloat16 bf16;

#define LRELU(v) ((v) >= 0.f ? (v) : 0.2f * (v))

__device__ __forceinline__ float b2f(bf16 v) { return __bfloat162float(v); }
__device__ __forceinline__ bf16 f2b(float v) { return __float2bfloat16(v); }

// load element i of an EXTERNAL tensor whose dtype is f32 (isf32=1) or bf16
__device__ __forceinline__ float eload(const void* p, long i, int isf32)
{
    return isf32 ? ((const float*)p)[i] : b2f(((const bf16*)p)[i]);
}

// ---------------------------------------------------------------------------
// Input-dtype detector: probe holds values ~N(0,0.05). Read as bf16: if the
// underlying data is f32, half the read elements are random mantissa bits and
// some are |v|>=1 or NaN with near-certainty. Writes 1 (f32) / 0 (bf16).
// ---------------------------------------------------------------------------
__global__ void dtype_detect_kernel(const void* probe, int n, int* flag)
{
    if (threadIdx.x == 0 && blockIdx.x == 0) {
        const bf16* e = (const bf16*)probe;
        int f32 = 0;
        for (int i = 0; i < n; ++i) {
            const float v = b2f(e[i]);
            if (!(v > -1.0f && v < 1.0f)) f32 = 1;   // catches NaN too
        }
        *flag = f32;
    }
}

// ---------------------------------------------------------------------------
// Generic fused 3x3 SAME conv with row-windowed src/dst. fp32 accumulate.
// PS = pixels/thread/axis (1 or 2). Tile = 16*PS. 256 threads/block.
// 16 output channels / block. Weights/bias/es/eb always EXTERNAL (dtype by
// *dflag). src external iff src_ext (batch biased by b_off); add_src external
// iff add_ext (batch biased by b_off independently of src).
// weoff = element offset into wgt (stacked per-branch weights).
// mode 0: dst = act(conv + bias)            (bf16, or fp32 if dst_f32)
// mode 1: (float*)dst += (conv*es[e]+eb[e]) * att[b,e,y,x]   (att fp32)
// mode 2: dst = resid + lrelu(conv+bias) * es[0]   (resid internal bf16)
// ---------------------------------------------------------------------------
template <int PS, int CIC>
__global__ void __launch_bounds__(256)
conv3x3_kernel(const void* __restrict__ src,
               const void* __restrict__ add_src,
               const void* __restrict__ add_scale_ptr,
               const void* __restrict__ wgt, long weoff,
               const void* __restrict__ bias,
               void* __restrict__ dst, int dst_f32,
               const bf16* __restrict__ resid,
               const float* __restrict__ att,
               const void* __restrict__ es_ptr,
               const void* __restrict__ eb_ptr,
               int e_idx,
               const int* __restrict__ dflag, int src_ext, int add_ext,
               int b_off,
               int B, int Cin, int Cout, int H, int W,
               int up, int act, int mode,
               int src_buf_row0, int src_buf_rows,
               int dst_buf_row0, int dst_buf_rows,
               int dst_y0, int dst_rows)
{
    constexpr int TILE = 16 * PS;
    constexpr int TIN  = TILE + 2;
    __shared__ float slds[TIN * TIN * CIC];
    __shared__ float wlds[16 * CIC * 9];

    const int ef = dflag[0];
    const int sf = src_ext ? ef : 0;
    const int af = add_ext ? ef : 0;
    const int sb = src_ext ? b_off : 0;   // batch bias for external src
    const int ab = add_ext ? b_off : 0;   // batch bias for external add_src

    const int coChunks = (Cout + 15) >> 4;
    const int tilesX   = W / TILE;
    const int tilesY   = dst_rows / TILE;

    int bid = blockIdx.x;
    const int coI = bid % coChunks; bid /= coChunks;
    const int tx  = bid % tilesX;   bid /= tilesX;
    const int ty  = bid % tilesY;
    const int b   = bid / tilesY;

    const int co0 = coI * 16;
    const int coN = min(16, Cout - co0);
    const int tid = threadIdx.x;
    const int py  = tid >> 4;
    const int px  = tid & 15;
    const int inW = up ? (W >> 1) : W;
    const int yb  = dst_y0 + ty * TILE;

    const float a_s = add_src ? eload(add_scale_ptr, 0, ef) : 0.0f;

    float acc[16][PS * PS];
#pragma unroll
    for (int i = 0; i < 16; ++i)
#pragma unroll
        for (int j = 0; j < PS * PS; ++j) acc[i][j] = 0.0f;

    for (int ci0 = 0; ci0 < Cin; ci0 += CIC) {
        const int cic = min(CIC, Cin - ci0);

        const int tot = TIN * TIN * cic;
        for (int i = tid; i < tot; i += 256) {
            const int c = i / (TIN * TIN);
            const int p = i % (TIN * TIN);
            const int iy = yb + p / TIN - 1;
            const int ix = tx * TILE + p % TIN - 1;
            float v = 0.0f;
            if (iy >= 0 && iy < H && ix >= 0 && ix < W) {
                const int sy = up ? (iy >> 1) : iy;
                const int sx = up ? (ix >> 1) : ix;
                const long row = (long)(sy - src_buf_row0);
                const long idxS = (((long)(b + sb) * Cin + ci0 + c) * src_buf_rows
                                   + row) * inW + sx;
                v = eload(src, idxS, sf);
                if (add_src) {
                    const long idxA = (((long)(b + ab) * Cin + ci0 + c) * src_buf_rows
                                       + row) * inW + sx;
                    v += a_s * eload(add_src, idxA, af);
                }
            }
            slds[i] = v;
        }

        const int wtot = 16 * cic * 9;
        for (int i = tid; i < wtot; i += 256) {
            const int co = i / (cic * 9);
            const int r  = i % (cic * 9);
            const int ci = r / 9;
            const int k  = r % 9;
            float v = 0.0f;
            if (co0 + co < Cout)
                v = eload(wgt, weoff + (((long)(co0 + co)) * Cin + ci0 + ci) * 9 + k, ef);
            wlds[(co * CIC + ci) * 9 + k] = v;
        }
        __syncthreads();

        for (int ci = 0; ci < cic; ++ci) {
            float in[(PS + 2) * (PS + 2)];
            const float* sp = &slds[ci * TIN * TIN + (py * PS) * TIN + px * PS];
#pragma unroll
            for (int i = 0; i < PS + 2; ++i)
#pragma unroll
                for (int j = 0; j < PS + 2; ++j)
                    in[i * (PS + 2) + j] = sp[i * TIN + j];

            const float* wbase = &wlds[ci * 9];
#pragma unroll
            for (int co = 0; co < 16; ++co) {
                const float* wp = wbase + co * CIC * 9;
                const float w0 = wp[0], w1 = wp[1], w2 = wp[2];
                const float w3 = wp[3], w4 = wp[4], w5 = wp[5];
                const float w6 = wp[6], w7 = wp[7], w8 = wp[8];
#pragma unroll
                for (int r = 0; r < PS; ++r)
#pragma unroll
                    for (int c = 0; c < PS; ++c) {
                        const float* q = &in[r * (PS + 2) + c];
                        float s = q[0] * w0 + q[1] * w1 + q[2] * w2
                                + q[PS + 2] * w3 + q[PS + 3] * w4 + q[PS + 4] * w5
                                + q[2 * (PS + 2)] * w6 + q[2 * (PS + 2) + 1] * w7
                                + q[2 * (PS + 2) + 2] * w8;
                        acc[co][r * PS + c] += s;
                    }
            }
        }
        __syncthreads();
    }

    const float es = es_ptr ? eload(es_ptr, e_idx, ef) : 1.0f;
    const float eb = eb_ptr ? eload(eb_ptr, e_idx, ef) : 0.0f;
#pragma unroll
    for (int r = 0; r < PS; ++r) {
#pragma unroll
        for (int c = 0; c < PS; ++c) {
            const int y  = yb + py * PS + r;
            const int xx = tx * TILE + px * PS + c;
            const int yr = y - dst_buf_row0;
            float attv = 0.0f;
            if (mode == 1)
                attv = att[(((long)b * 8 + e_idx) * H + y) * W + xx];
#pragma unroll
            for (int co = 0; co < 16; ++co) {
                if (co < coN) {
                    float v = acc[co][r * PS + c];
                    if (bias) v += eload(bias, co0 + co, ef);
                    const long di = (((long)b * Cout + co0 + co) * dst_buf_rows
                                     + yr) * W + xx;
                    if (mode == 0) {
                        if (act) v = LRELU(v);
                        if (dst_f32) ((float*)dst)[di] = v;
                        else         ((bf16*)dst)[di]  = f2b(v);
                    } else if (mode == 1) {
                        ((float*)dst)[di] += (v * es + eb) * attv;
                    } else {
                        const float lr = LRELU(v);
                        ((bf16*)dst)[di] = f2b(b2f(resid[di]) + lr * es);
                    }
                }
            }
        }
    }
}

// ---------------------------------------------------------------------------
__global__ void __launch_bounds__(256)
gn_silu_kernel(bf16* __restrict__ d, const void* __restrict__ g,
               const void* __restrict__ be, const int* __restrict__ dflag,
               int C, int gsize, int HW)
{
    const int ef = dflag[0];
    const int groups = C / gsize;
    const int blk = blockIdx.x;
    const int b  = blk / groups;
    const int gr = blk % groups;
    const long base = ((long)b * C + (long)gr * gsize) * HW;
    const int N = gsize * HW;

    float s = 0.0f, ss = 0.0f;
    for (int i = threadIdx.x; i < N; i += 256) {
        const float v = b2f(d[base + i]);
        s += v;
        ss += v * v;
    }
    __shared__ float rs[256], rss[256];
    rs[threadIdx.x] = s;
    rss[threadIdx.x] = ss;
    __syncthreads();
    for (int o = 128; o > 0; o >>= 1) {
        if (threadIdx.x < o) {
            rs[threadIdx.x]  += rs[threadIdx.x + o];
            rss[threadIdx.x] += rss[threadIdx.x + o];
        }
        __syncthreads();
    }
    __shared__ float mean_s, inv_s;
    if (threadIdx.x == 0) {
        const float mean = rs[0] / (float)N;
        const float var  = rss[0] / (float)N - mean * mean;
        mean_s = mean;
        inv_s  = rsqrtf(var + 1e-5f);
    }
    __syncthreads();
    const float mean = mean_s, inv = inv_s;
    for (int i = threadIdx.x; i < N; i += 256) {
        const int c = gr * gsize + i / HW;
        const float v  = b2f(d[base + i]);
        const float xn = (v - mean) * inv * eload(g, c, ef) + eload(be, c, ef);
        d[base + i] = f2b(xn / (1.0f + expf(-xn)));
    }
}

__global__ void __launch_bounds__(256)
softmax_t_kernel(float* __restrict__ m, int BHW, int HW, float invtemp)
{
    const int i = blockIdx.x * 256 + threadIdx.x;
    if (i >= BHW) return;
    const int b = i / HW;
    const int p = i % HW;
    const long base = (long)b * 8 * HW + p;
    float v[8];
    float mx = -1e30f;
#pragma unroll
    for (int t = 0; t < 8; ++t) {
        v[t] = m[base + (long)t * HW] * invtemp;
        mx = fmaxf(mx, v[t]);
    }
    float s = 0.0f;
#pragma unroll
    for (int t = 0; t < 8; ++t) {
        v[t] = expf(v[t] - mx);
        s += v[t];
    }
    const float r = 1.0f / s;
#pragma unroll
    for (int t = 0; t < 8; ++t)
        m[base + (long)t * HW] = v[t] * r;
}

__global__ void __launch_bounds__(256)
combine_kernel(const bf16* __restrict__ x0, const float* __restrict__ acc,
               const void* __restrict__ ss, const int* __restrict__ dflag,
               bf16* __restrict__ out, long n)
{
    const long i = (long)blockIdx.x * 256 + threadIdx.x;
    if (i < n) out[i] = f2b(b2f(x0[i]) + acc[i] * eload(ss, 0, dflag[0]));
}

__global__ void __launch_bounds__(256)
zero_kernel(float* __restrict__ p, long n)
{
    const long i = (long)blockIdx.x * 256 + threadIdx.x;
    if (i < n) p[i] = 0.0f;
}

// ---------------------------------------------------------------------------
static const int* g_dflag;

static void launch_conv_w(hipStream_t st, const void* src, const void* wgt,
                          const void* bias, void* dst, int dst_f32,
                          int B, int Cin, int Cout, int H, int W,
                          int up, int act,
                          int src_buf_row0, int src_buf_rows,
                          int dst_buf_row0, int dst_buf_rows,
                          int dst_y0, int dst_rows,
                          int src_ext = 0, int b_off = 0,
                          const void* add_src = nullptr,
                          const void* add_scale = nullptr, int add_ext = 0,
                          long weoff = 0,
                          int mode = 0, const bf16* resid = nullptr,
                          const float* att = nullptr,
                          const void* es = nullptr, const void* eb = nullptr,
                          int eidx = 0)
{
    const bool ps2 = (dst_rows % 32 == 0) && (W % 32 == 0) && (dst_y0 % 32 == 0);
    const int TILE = ps2 ? 32 : 16;
    const int blocks = B * (dst_rows / TILE) * (W / TILE) * ((Cout + 15) / 16);
    if (ps2)
        conv3x3_kernel<2, 8><<<blocks, 256, 0, st>>>(
            src, add_src, add_scale, wgt, weoff, bias, dst, dst_f32, resid, att,
            es, eb, eidx, g_dflag, src_ext, add_ext, b_off,
            B, Cin, Cout, H, W, up, act, mode,
            src_buf_row0, src_buf_rows, dst_buf_row0, dst_buf_rows, dst_y0, dst_rows);
    else
        conv3x3_kernel<1, 16><<<blocks, 256, 0, st>>>(
            src, add_src, add_scale, wgt, weoff, bias, dst, dst_f32, resid, att,
            es, eb, eidx, g_dflag, src_ext, add_ext, b_off,
            B, Cin, Cout, H, W, up, act, mode,
            src_buf_row0, src_buf_rows, dst_buf_row0, dst_buf_rows, dst_y0, dst_rows);
}

static void launch_conv(hipStream_t st, const void* src, const void* wgt,
                        const void* bias, void* dst, int dst_f32,
                        int B, int Cin, int Cout, int H, int W,
                        int up, int act,
                        int src_ext = 0, int b_off = 0,
                        const void* add_src = nullptr,
                        const void* add_scale = nullptr, int add_ext = 0,
                        long weoff = 0,
                        int mode = 0, const bf16* resid = nullptr,
                        const float* att = nullptr,
                        const void* es = nullptr, const void* eb = nullptr,
                        int eidx = 0)
{
    launch_conv_w(st, src, wgt, bias, dst, dst_f32, B, Cin, Cout, H, W, up, act,
                  0, up ? (H >> 1) : H, 0, H, 0, H,
                  src_ext, b_off, add_src, add_scale, add_ext, weoff,
                  mode, resid, att, es, eb, eidx);
}

extern "C" void kernel_launch(void* const* d_in, const int* in_sizes, int n_in,
                              void* d_out, int out_size, void* d_ws, size_t ws_size,
                              hipStream_t stream)
{
    const void* x_all   = d_in[0];
    const void* sp_all  = d_in[1];
    const void* nz_all  = d_in[2];
    const void* init_w  = d_in[3];
    const void* init_b  = d_in[4];
    const void* pre_w   = d_in[5];
    const void* tw0     = d_in[6];
    const void* tw1     = d_in[7];
    const void* tw2     = d_in[8];
    const void* tw3     = d_in[9];
    const void* tscale  = d_in[10];
    const void* tbias   = d_in[11];
    const void* nscale  = d_in[12];
    const void* sscale  = d_in[13];
    const void* pscale  = d_in[14];
    const void* post_w  = d_in[15];
    const void* post_b  = d_in[16];
    const void* m1_w    = d_in[17];
    const void* m1_b    = d_in[18];
    const void* m1_g    = d_in[19];
    const void* m1_be   = d_in[20];
    const void* m2_w    = d_in[21];
    const void* m2_g    = d_in[22];
    const void* m2_be   = d_in[23];
    const void* u1a_w   = d_in[24];
    const void* u1b_w   = d_in[25];
    const void* u1b_g   = d_in[26];
    const void* u1b_be  = d_in[27];
    const void* u2a_w   = d_in[28];
    const void* u2b_w   = d_in[29];
    const void* u2b_g   = d_in[30];
    const void* u2b_be  = d_in[31];
    const void* mf_w    = d_in[32];
    const void* up1_w   = d_in[33];
    const void* up1_b   = d_in[34];
    const void* up2_w   = d_in[35];
    const void* up2_b   = d_in[36];
    const void* hr_w    = d_in[37];
    const void* hr_b    = d_in[38];
    const void* fin_w   = d_in[39];
    const void* fin_b   = d_in[40];
    (void)in_sizes; (void)n_in; (void)out_size;

    // dtype flag in first 256 bytes of ws
    char* wsb = (char*)d_ws;
    int* dflag = (int*)wsb;
    g_dflag = dflag;
    dtype_detect_kernel<<<1, 64, 0, stream>>>(tw1, 128, dflag);

    // schedule: batch chunk bc, tail strip S
    int bc = 1, S = 16, tc = 1;
    for (int c = 16; c >= 1; c >>= 1) {
        const size_t fixed = 256u + (size_t)c * 1703936u;
        if (ws_size < fixed) continue;
        const size_t rem = ws_size - fixed;
        if (rem < (size_t)c * 2621440u) continue;
        if (rem >= 18874368u) {
            bc = c; S = 256;
            tc = (int)(rem / 18874368u); if (tc > c) tc = c;
            break;
        } else if (rem >= 9437184u)  { bc = c; S = 64; tc = 1; break; }
        else if (rem >= 7340032u)    { bc = c; S = 32; tc = 1; break; }
        else if (rem >= 6291456u)    { bc = c; S = 16; tc = 1; break; }
    }

    float* M    = (float*)(wsb + 256);
    float* ACC  = (float*)(wsb + 256 + (size_t)bc * 131072u);
    bf16*  OUT2 = (bf16*)(wsb + 256 + (size_t)bc * 1179648u);
    bf16*  A    = (bf16*)(wsb + 256 + (size_t)bc * 1703936u);

    for (int b0 = 0; b0 < 16; b0 += bc) {
        float* outp = (float*)d_out + (size_t)b0 * 3 * 65536;   // f32 output!

        // ---- phase 1: multiplexer ----
        bf16* f1 = A;
        bf16* f2 = A + (size_t)bc * 65536;
        bf16* g1 = A + (size_t)bc * 131072;
        bf16* g2 = A + (size_t)bc * 262144;
        bf16* h1 = A + (size_t)bc * 393216;
        bf16* h2 = A + (size_t)bc * 655360;

        launch_conv(stream, sp_all, m1_w, m1_b, f1, 0, bc, 256, 256, 16, 16, 0, 0,
                    1, b0);
        gn_silu_kernel<<<bc * 8, 256, 0, stream>>>(f1, m1_g, m1_be, dflag, 256, 32, 256);
        launch_conv(stream, f1, m2_w, nullptr, f2, 0, bc, 256, 256, 16, 16, 0, 0);
        gn_silu_kernel<<<bc * 8, 256, 0, stream>>>(f2, m2_g, m2_be, dflag, 256, 32, 256);
        launch_conv(stream, f2, u1a_w, nullptr, g1, 0, bc, 256, 128, 32, 32, 1, 0);
        launch_conv(stream, g1, u1b_w, nullptr, g2, 0, bc, 128, 128, 32, 32, 0, 0);
        gn_silu_kernel<<<bc * 8, 256, 0, stream>>>(g2, u1b_g, u1b_be, dflag, 128, 16, 1024);
        launch_conv(stream, g2, u2a_w, nullptr, h1, 0, bc, 128, 64, 64, 64, 1, 0);
        launch_conv(stream, h1, u2b_w, nullptr, h2, 0, bc, 64, 64, 64, 64, 0, 0);
        gn_silu_kernel<<<bc * 8, 256, 0, stream>>>(h2, u2b_g, u2b_be, dflag, 64, 8, 4096);
        launch_conv(stream, h2, mf_w, nullptr, M, 1, bc, 64, 8, 64, 64, 0, 0);
        softmax_t_kernel<<<(bc * 4096 + 255) / 256, 256, 0, stream>>>(
            M, bc * 4096, 4096, 1.0f / 20.0f);

        // ---- phase 2: stem + branches ----
        bf16* x0   = A;
        bf16* xsp  = A + (size_t)bc * 262144;
        bf16* ping = A + (size_t)bc * 524288;
        bf16* pong = A + (size_t)bc * 917504;

        launch_conv(stream, x_all, init_w, init_b, x0, 0, bc, 3, 64, 64, 64, 0, 0,
                    1, b0);
        launch_conv(stream, x0, pre_w, nullptr, xsp, 0, bc, 64, 64, 64, 64, 0, 0,
                    0, b0, nz_all, nscale, 1);

        const long accn = (long)bc * 262144;
        zero_kernel<<<(int)((accn + 255) / 256), 256, 0, stream>>>(ACC, accn);

        for (int t = 0; t < 8; ++t) {
            launch_conv(stream, xsp,  tw0, nullptr, ping, 0, bc, 64, 96, 64, 64, 0, 1,
                        0, 0, nullptr, nullptr, 0, (long)t * 96 * 64 * 9);
            launch_conv(stream, ping, tw1, nullptr, pong, 0, bc, 96, 96, 64, 64, 0, 1,
                        0, 0, nullptr, nullptr, 0, (long)t * 96 * 96 * 9);
            launch_conv(stream, pong, tw2, nullptr, ping, 0, bc, 96, 96, 64, 64, 0, 1,
                        0, 0, nullptr, nullptr, 0, (long)t * 96 * 96 * 9);
            launch_conv(stream, ping, tw3, nullptr, ACC, 1, bc, 96, 64, 64, 64, 0, 0,
                        0, 0, nullptr, nullptr, 0, (long)t * 64 * 96 * 9,
                        1, nullptr, M, tscale, tbias, t);
        }

        bf16* outc = xsp;
        combine_kernel<<<(int)((accn + 255) / 256), 256, 0, stream>>>(
            x0, ACC, sscale, dflag, outc, accn);

        launch_conv(stream, outc, post_w, post_b, OUT2, 0, bc, 64, 64, 64, 64, 0, 0,
                    0, 0, nullptr, nullptr, 0, 0,
                    2, outc, nullptr, pscale, nullptr, 0);

        // ---- phase 3: tail (f32 output) ----
        if (S == 256) {
            bf16* a1 = A;
            bf16* a2 = A + (size_t)tc * 1048576;
            bf16* a3 = A + (size_t)tc * 5242880;
            for (int s0 = 0; s0 < bc; s0 += tc) {
                const int cur = (tc < bc - s0) ? tc : (bc - s0);
                const bf16* src_c = OUT2 + (size_t)s0 * 64 * 4096;
                float* out_c = outp + (size_t)s0 * 3 * 65536;
                launch_conv(stream, src_c, up1_w, up1_b, a1, 0, cur, 64, 64, 128, 128, 1, 1);
                launch_conv(stream, a1,   up2_w, up2_b, a2, 0, cur, 64, 64, 256, 256, 1, 1);
                launch_conv(stream, a2,   hr_w,  hr_b,  a3, 0, cur, 64, 64, 256, 256, 0, 1);
                launch_conv(stream, a3,   fin_w, fin_b, out_c, 1, cur, 64, 3, 256, 256, 0, 0);
            }
        } else {
            bf16* a1  = A;
            bf16* a2s = A + 1048576;
            bf16* a3s = a2s + (size_t)(S + 64) * 16384;
            for (int i = 0; i < bc; ++i) {
                const bf16* src_i = OUT2 + (size_t)i * 64 * 4096;
                float* out_i = outp + (size_t)i * 3 * 65536;
                launch_conv(stream, src_i, up1_w, up1_b, a1, 0, 1, 64, 64, 128, 128, 1, 1);
                for (int r0 = 0; r0 < 256; r0 += S) {
                    const int r1 = r0 + S;
                    const int w2a = (r0 - 32 > 0) ? r0 - 32 : 0;
                    const int w2b = (r1 + 32 < 256) ? r1 + 32 : 256;
                    const int w3a = (r0 - 16 > 0) ? r0 - 16 : 0;
                    const int w3b = (r1 + 16 < 256) ? r1 + 16 : 256;
                    launch_conv_w(stream, a1, up2_w, up2_b, a2s, 0,
                                  1, 64, 64, 256, 256, 1, 1,
                                  0, 128, w2a, w2b - w2a, w2a, w2b - w2a);
                    launch_conv_w(stream, a2s, hr_w, hr_b, a3s, 0,
                                  1, 64, 64, 256, 256, 0, 1,
                                  w2a, w2b - w2a, w3a, w3b - w3a, w3a, w3b - w3a);
                    launch_conv_w(stream, a3s, fin_w, fin_b, out_i, 1,
                                  1, 64, 3, 256, 256, 0, 0,
                                  w3a, w3b - w3a, 0, 256, r0, S);
                }
            }
        }
    }
}